// Round 2
// 227.495 us; speedup vs baseline: 1.0052x; 1.0052x over previous
//
#include <hip/hip_runtime.h>

// Loss = L1*sl1(1,iou) + L2*sl1(t[:4],p[:4]) + L3*sl1(t[12],p[12]) + 0.5*L4*sl1(t[4:12],p[4:12])
// shapes: (B=256, N=8192, F=13) fp32. B*N = 2^21 rows.
//
// stage1: per-WAVE independent pipelines (no __syncthreads in the main loop).
// Each wave owns groups of 64 rows (64*52 B = 3328 B per tensor), staged into a
// private 2-deep LDS ring via __builtin_amdgcn_global_load_lds (3x16B-lane +
// 1x4B-lane per tensor = 8 loads/group). Progress is gated by counted
// s_waitcnt vmcnt(8) — the next group's 8 loads stay in flight across every
// compute phase (T3/T4: never drain vmcnt(0) in the loop). This removes the
// round-0 structure's stall: __syncthreads forced a compiler-emitted
// s_waitcnt vmcnt(0) that drained the just-issued prefetch every iteration
// (measured 2.6 TB/s effective, VALUBusy 10%, nothing saturated).
//
// Ring depth is 2 (not 3): lds[4][2][2][832] = 53,248 B — within the 64 KiB
// static __shared__ per-workgroup limit (the 3-deep variant at 79,872 B
// exceeded it => round-1 launch failure). Little's law: ~8-16 loads
// (3.3-6.6 KB) outstanding per wave x 8 waves/CU ≈ 40 KB/CU in flight vs
// ~9 KB/CU needed for 6.3 TB/s at ~900 cy latency — depth 2 suffices.
//
// 512 blocks * 4 waves = 2048 waves; 32768 groups => exactly 16 groups/wave.
// stage2: one block sums 512 partials.

#define NGRP   32768            // (B*N)/64 row-groups
#define GBYTES 3328             // bytes per tensor per group (64 rows * 52 B)
#define GFLOAT 832              // floats per tensor per group
#define NBUF   2
#define NBLK   512              // 2 blocks/CU * 256 CU
#define NWAVE  (NBLK * 4)       // 2048 waves
#define GPW    (NGRP / NWAVE)   // 16 groups per wave

typedef const __attribute__((address_space(1))) float gfloat;
typedef __attribute__((address_space(3))) float lfloat;

__device__ __forceinline__ float sl1(float d) {
    d = fabsf(d);
    return d < 1.0f ? 0.5f * d * d : d - 0.5f;
}

__global__ __launch_bounds__(256) void loss_stage1(const float* __restrict__ T,
                                                   const float* __restrict__ P,
                                                   float* __restrict__ partial) {
    // [wave][buf][tensor][floats] — each wave touches only its own slice.
    __shared__ float lds[4][NBUF][2][GFLOAT];   // 53,248 B (< 64 KiB limit)
    __shared__ float wred[4];

    const int tid  = threadIdx.x;
    const int lane = tid & 63;
    const int wv   = tid >> 6;
    const int wid  = blockIdx.x * 4 + wv;    // global wave id, 0..NWAVE-1

    // Stage group g into this wave's buffer b: 8 async direct-to-LDS loads.
    // LDS dest follows the HW rule (wave-uniform base + lane*size); layout in
    // LDS is identical to global, so no swizzle. The lane*13-float row read
    // below is a 2-way bank alias => free (m136).
    auto stage = [&](int g, int b) {
        const char* tb = (const char*)T + (long long)g * GBYTES;
        const char* pb = (const char*)P + (long long)g * GBYTES;
        lfloat* lt = (lfloat*)&lds[wv][b][0][0];
        lfloat* lp = (lfloat*)&lds[wv][b][1][0];
#pragma unroll
        for (int s = 0; s < 3; ++s) {
            __builtin_amdgcn_global_load_lds((gfloat*)(tb + s * 1024 + lane * 16),
                                             lt + s * 256 + lane * 4, 16, 0, 0);
            __builtin_amdgcn_global_load_lds((gfloat*)(pb + s * 1024 + lane * 16),
                                             lp + s * 256 + lane * 4, 16, 0, 0);
        }
        __builtin_amdgcn_global_load_lds((gfloat*)(tb + 3072 + lane * 4),
                                         lt + 768 + lane, 4, 0, 0);
        __builtin_amdgcn_global_load_lds((gfloat*)(pb + 3072 + lane * 4),
                                         lp + 768 + lane, 4, 0, 0);
    };

    // Prime the ring: 2 groups (16 loads) in flight before the first compute.
    stage(wid, 0);
    stage(wid + NWAVE, 1);

    float acc = 0.0f;

    for (int i = 0; i < GPW; ++i) {
        // Counted wait: oldest 8 loads (this iteration's buffer) complete;
        // the next group's 8 stay outstanding across the compute.
        if (i < GPW - 1) asm volatile("s_waitcnt vmcnt(8)" ::: "memory");
        else             asm volatile("s_waitcnt vmcnt(0)" ::: "memory");
        __builtin_amdgcn_sched_barrier(0);

        const int buf = i & 1;
        const float* t = &lds[wv][buf][0][0];
        const float* p = &lds[wv][buf][1][0];
        const int rb = lane * 13;

        float t0 = t[rb + 0], t1 = t[rb + 1], t2 = t[rb + 2], t3 = t[rb + 3];
        float p0 = p[rb + 0], p1 = p[rb + 1], p2 = p[rb + 2], p3 = p[rb + 3];

        float s2 = sl1(t0 - p0) + sl1(t1 - p1) + sl1(t2 - p2) + sl1(t3 - p3);

        float s4 = 0.0f;
#pragma unroll
        for (int f = 4; f < 12; ++f) s4 += sl1(t[rb + f] - p[rb + f]);

        float s3 = sl1(t[rb + 12] - p[rb + 12]);

        float xx1 = fmaxf(t0, p0);
        float yy1 = fmaxf(t1, p1);
        float xx2 = fminf(t2, p2);
        float yy2 = fminf(t3, p3);
        float w  = fmaxf(xx2 - xx1, 0.0f);
        float h  = fmaxf(yy2 - yy1, 0.0f);
        float inter = w * h;
        float a1 = (t2 - t0) * (t3 - t1);
        float a2 = (p2 - p0) * (p3 - p1);
        float iou = inter / (a1 + a2 - inter + 1e-7f);
        float s1 = sl1(1.0f - iou);

        // Exact power-of-two mean weights: B*N = 2^21.
        constexpr float W1 = 1.0f / 2097152.0f;    // 1/(B*N)
        constexpr float W2 = 1.0f / 8388608.0f;    // 1/(B*N*4)
        constexpr float W3 = 1.0f / 2097152.0f;    // 1/(B*N)
        constexpr float W4 = 1.0f / 33554432.0f;   // 0.5/(B*N*8)
        acc += W1 * s1 + W2 * s2 + W3 * s3 + W4 * s4;

        // Re-stage the just-consumed buffer with group i+2 (after the LDS
        // reads above in program order; its LDS write returns far later than
        // the already-issued ds_reads complete — standard double-buffer).
        if (i + 2 < GPW) stage(wid + (i + 2) * NWAVE, buf);
    }

    // Block reduction: wave64 shuffle -> 4-wave LDS -> one partial per block.
#pragma unroll
    for (int off = 32; off > 0; off >>= 1)
        acc += __shfl_down(acc, off, 64);
    if (lane == 0) wred[wv] = acc;
    __syncthreads();
    if (tid == 0)
        partial[blockIdx.x] = wred[0] + wred[1] + wred[2] + wred[3];
}

__global__ __launch_bounds__(256) void loss_stage2(const float* __restrict__ partial,
                                                   float* __restrict__ out) {
    __shared__ float wred[4];
    const int tid = threadIdx.x;
    float a = 0.0f;
    for (int i = tid; i < NBLK; i += 256) a += partial[i];
#pragma unroll
    for (int off = 32; off > 0; off >>= 1)
        a += __shfl_down(a, off, 64);
    if ((tid & 63) == 0) wred[tid >> 6] = a;
    __syncthreads();
    if (tid == 0) out[0] = wred[0] + wred[1] + wred[2] + wred[3];
}

extern "C" void kernel_launch(void* const* d_in, const int* in_sizes, int n_in,
                              void* d_out, int out_size, void* d_ws, size_t ws_size,
                              hipStream_t stream) {
    const float* targets = (const float*)d_in[0];
    const float* preds   = (const float*)d_in[1];
    float* out     = (float*)d_out;
    float* partial = (float*)d_ws;   // NBLK floats of scratch

    loss_stage1<<<NBLK, 256, 0, stream>>>(targets, preds, partial);
    loss_stage2<<<1, 256, 0, stream>>>(partial, out);
}